// Round 9
// baseline (338.127 us; speedup 1.0000x reference)
//
#include <hip/hip_runtime.h>
#include <hip/hip_bf16.h>
#include <stdint.h>

#define N_TOKENS   65536
#define IN_FEAT    512
#define OUT_FEAT   512
#define NUM_EXPERT 64
#define BK 32
#define SK 36                    // padded LDS stride (mid-path kernel only)
#define K_STEPS (IN_FEAT / BK)   // 16
#define NRANGE 256               // token ranges (256 tokens each)

// BIG-path GEMM tile: 256 x 256, 512 threads (8 waves, 2x4), acc 128x64/wave.
// BM=256 halves B-panel re-reads vs BM=128 (the measured LLC-BW bottleneck).
#define BMB 256
#define BNB 256
#define NCOLB (OUT_FEAT / BNB)       // 2
#define MAX_TILES_B 384              // true worst case: 256 + 64 = 320
// MID-path GEMM tile: 128 x 128, 256 threads
#define BMM 128
#define BNM 128
#define NCOLM (OUT_FEAT / BNM)       // 4
#define MAX_TILES_M 640              // true worst case: 512 + 64 = 576

// ws layout (int32 units):
//   [197] tile_count  [200..2120) tiles (e,start,cnt) up to 640
//   [2048..34816)  order ushort[65536] (128 KB)   (tiles actually <=576 -> no overlap)
//   [34816..51200) counts matrix cnt[range][expert] = 256x64 ints (64 KB)
// BIG extension (byte offsets):
//   [212992 ..)              bf16 copy of inp, TOKEN order (67,108,864 B)
//   [212992+2*INP_ELEMS ..)  bf16 copy of weight (33,554,432 B)
#define WS_NTILES 197
#define WS_TILES  200
#define WS_ORDER  2048
#define WS_CNT    34816
#define WS_META_NEEDED 204800    // bytes: through end of counts matrix

#define INP_ELEMS (N_TOKENS * IN_FEAT)               // 33,554,432
#define W_ELEMS   (NUM_EXPERT * OUT_FEAT * IN_FEAT)  // 16,777,216
#define WS_BF16_OFF 212992
#define WS_BIG ((size_t)WS_BF16_OFF + 2ull * INP_ELEMS + 2ull * W_ELEMS)  // ~100.9 MB

typedef __attribute__((ext_vector_type(8))) short bf16x8;
typedef __attribute__((ext_vector_type(4))) float f32x4;

__device__ __forceinline__ float b2f(short v) {
    union { float f; unsigned u; } z;
    z.u = ((unsigned)(unsigned short)v) << 16;
    return z.f;
}

__device__ __forceinline__ unsigned pk2(float a, float b) {
    union { __hip_bfloat16 h; unsigned short u; } x, y;
    x.h = __float2bfloat16(a);
    y.h = __float2bfloat16(b);
    return ((unsigned)y.u << 16) | (unsigned)x.u;
}

__device__ __forceinline__ unsigned short f2bu(float a) {
    union { __hip_bfloat16 h; unsigned short u; } x;
    x.h = __float2bfloat16(a);
    return x.u;
}

// async global->LDS, 16B per lane; LDS dest is wave-uniform base + lane*16
__device__ __forceinline__ void gll16(const void* g, short* l) {
    __builtin_amdgcn_global_load_lds(
        (const __attribute__((address_space(1))) unsigned*)g,
        (__attribute__((address_space(3))) unsigned*)l, 16, 0, 0);
}

// dtype detect by one wave: bf16-pair data has low-u16 exponent fields in the
// plausible band; fp32 low-u16 is random mantissa bits. Deterministic.
__device__ __forceinline__ int detect_wave(const unsigned* __restrict__ inw, int lane) {
    int cnt = 0;
    #pragma unroll
    for (int i = 0; i < 16; ++i) {
        unsigned u = inw[lane * 16 + i];
        unsigned lo = u & 0xFFFFu;
        unsigned ec = (lo >> 7) & 0xFFu;
        if (lo == 0u || (ec >= 90u && ec <= 131u)) cnt++;
    }
    #pragma unroll
    for (int d = 32; d > 0; d >>= 1) cnt += __shfl_down(cnt, d, 64);
    return (cnt >= 512) ? 0 : 1;   // valid on lane 0: 0=bf16, 1=fp32
}

// ---------------------------------------------------------------------------
// k_count: 256 blocks, each histograms its own 256-token range. ~3 us.
// ---------------------------------------------------------------------------
__global__ __launch_bounds__(256) void k_count(const int* __restrict__ gate,
                                               int* __restrict__ ws) {
    __shared__ int h[NUM_EXPERT];
    int t = threadIdx.x;
    if (t < NUM_EXPERT) h[t] = 0;
    __syncthreads();
    int g = gate[blockIdx.x * 256 + t] & 63;
    atomicAdd(&h[g], 1);
    __syncthreads();
    if (t < NUM_EXPERT) ws[WS_CNT + blockIdx.x * 64 + t] = h[t];
}

// ---------------------------------------------------------------------------
// k_plan_cvt: blocks 0..255 derive the plan from the counts matrix (L2-hot),
// rank their own 256 tokens via LDS cursors, write order (block 0 also writes
// tile descriptors with runtime tile height 1<<lg_bm), then JOIN the streaming
// conversion. All blocks: (big+fp32) grid-stride fp32->bf16 conversion of inp
// (TOKEN order) + weight; NT loads on read-once fp32 sources, normal stores
// keep the bf16 copies LLC-hot. Plan cost hides entirely under conversion.
// ---------------------------------------------------------------------------
__global__ __launch_bounds__(256) void k_plan_cvt(
        const int* __restrict__ gate,
        const void* __restrict__ inp_,
        const void* __restrict__ weight_,
        int* __restrict__ ws,
        int big, int lg_bm) {
    __shared__ int sFlag;
    int t = threadIdx.x;
    int lane = t & 63;
    if (t < 64) {
        int f = detect_wave((const unsigned*)inp_, lane);
        if (t == 0) sFlag = f;
    }
    __syncthreads();
    int flag = sFlag;

    if (blockIdx.x < NRANGE) {
        __shared__ int pAll[4][NUM_EXPERT];
        __shared__ int pPre[4][NUM_EXPERT];
        __shared__ int sCur[NUM_EXPERT];
        int b = blockIdx.x;
        int e = t & 63;
        int q = t >> 6;
        const int* cnt = ws + WS_CNT;
        int sAll = 0, sPre = 0;
        for (int r = q * 64; r < q * 64 + 64; ++r) {
            int v = cnt[r * 64 + e];
            sAll += v;
            if (r < b) sPre += v;
        }
        pAll[q][e] = sAll;
        pPre[q][e] = sPre;
        __syncthreads();
        if (t < 64) {
            int T = pAll[0][lane] + pAll[1][lane] + pAll[2][lane] + pAll[3][lane];
            int P = pPre[0][lane] + pPre[1][lane] + pPre[2][lane] + pPre[3][lane];
            int ps = T;
            #pragma unroll
            for (int d = 1; d < 64; d <<= 1) { int v = __shfl_up(ps, d, 64); if (lane >= d) ps += v; }
            int off = ps - T;            // exclusive token prefix of expert `lane`
            sCur[lane] = off + P;        // this block's base for expert `lane`
            if (b == 0) {
                int bm = 1 << lg_bm;
                int nt = (T + bm - 1) >> lg_bm;
                int pt = nt;
                #pragma unroll
                for (int d = 1; d < 64; d <<= 1) { int v = __shfl_up(pt, d, 64); if (lane >= d) pt += v; }
                int tb = pt - nt;
                for (int j = 0; j < nt; ++j) {
                    int* tp = ws + WS_TILES + (tb + j) * 3;
                    tp[0] = lane;
                    tp[1] = off + (j << lg_bm);
                    int rem = T - (j << lg_bm);
                    tp[2] = rem < bm ? rem : bm;
                }
                if (lane == 63) ws[WS_NTILES] = pt;
            }
        }
        __syncthreads();

        unsigned short* order = (unsigned short*)(ws + WS_ORDER);
        int tok = b * 256 + t;
        int ge = gate[tok] & 63;
        int pos = atomicAdd(&sCur[ge], 1);
        if ((unsigned)pos < (unsigned)N_TOKENS) order[pos] = (unsigned short)tok;
        // fall through: join streaming conversion
    }

    // ---- streaming conversion (big + fp32 only), all blocks ----
    if (!big || flag != 1) return;
    const float* inpf = (const float*)inp_;
    const float* wf   = (const float*)weight_;
    short* bi = (short*)((char*)ws + WS_BF16_OFF);
    short* bw = bi + INP_ELEMS;
    const long long NC = (long long)(INP_ELEMS + W_ELEMS) / 8;  // 8-float chunks
    long long idx = (long long)blockIdx.x * 256 + t;
    long long stride = (long long)gridDim.x * 256;
    for (long long c = idx; c < NC; c += stride) {
        long long f8 = c * 8;
        const f32x4* s;
        uint4* d;
        if (f8 < INP_ELEMS) {
            s = (const f32x4*)(inpf + f8);
            d = (uint4*)(bi + f8);
        } else {
            long long g = f8 - INP_ELEMS;
            s = (const f32x4*)(wf + g);
            d = (uint4*)(bw + g);
        }
        f32x4 x = __builtin_nontemporal_load(s);
        f32x4 y = __builtin_nontemporal_load(s + 1);
        *d = (uint4){pk2(x[0], x[1]), pk2(x[2], x[3]),
                     pk2(y[0], y[1]), pk2(y[2], y[3])};
    }
}

// Fenced drain + barrier (R4/R7-proven; counted-vmcnt raced on HW in R5/R6).
#define DRAIN_BARRIER()                                                        \
    asm volatile("s_waitcnt vmcnt(0)" ::: "memory");                           \
    asm volatile("s_barrier" ::: "memory")

// big-path: 4 gll16 per lane per K-step (A segs 2w,2w+1; B segs 2w,2w+1)
#define STAGE_B(kk, pa0, pa1, pb0, pb1)                                        \
    gll16(gA0 + (size_t)(kk) * 64, (pa0));                                     \
    gll16(gA1 + (size_t)(kk) * 64, (pa1));                                     \
    gll16(gB0 + (size_t)(kk) * 64, (pb0));                                     \
    gll16(gB1 + (size_t)(kk) * 64, (pb1));

// big-path compute: 8 M-frags x 4 N-frags = 32 MFMA per lane per K-step
#define COMPUTE_B(pA, pB)                                                      \
    {                                                                          \
        bf16x8 b_[4];                                                          \
        _Pragma("unroll")                                                      \
        for (int j_ = 0; j_ < 4; ++j_)                                         \
            b_[j_] = *(const bf16x8*)((pB) + j_ * 16 * BK);                    \
        _Pragma("unroll")                                                      \
        for (int i_ = 0; i_ < 8; ++i_) {                                       \
            bf16x8 a_ = *(const bf16x8*)((pA) + i_ * 16 * BK);                 \
            _Pragma("unroll")                                                  \
            for (int j_ = 0; j_ < 4; ++j_)                                     \
                acc[i_][j_] = __builtin_amdgcn_mfma_f32_16x16x32_bf16(         \
                    a_, b_[j_], acc[i_][j_], 0, 0, 0);                         \
        }                                                                      \
    }

// ---------- BIG path GEMM: 256x256 tile, 512 threads (8 waves, 2x4) ----------
// BM=256 halves B-panel LLC re-reads (the measured bottleneck: ~440 MB cache
// reads at ~5.5 TB/s = the 80 us). Per K-step: issue STAGE(k+1) into the other
// buffer, COMPUTE(k) (loads drain UNDER the MFMAs), vmcnt(0)+barrier.
// Source-side XOR chunk swizzle + same XOR on frag reads (row+16 shares the
// same XOR term since 16>>1 == 0 mod 4). Items XCD-chunked for L2 locality.
__global__ __launch_bounds__(512) void k_moe_gemm_big(
        const void* __restrict__ inp_,
        const void* __restrict__ weight_,
        void* __restrict__ out_,
        const int* __restrict__ ws) {
    __shared__ __align__(16) short sA0[BMB * BK], sA1[BMB * BK];  // 16 KB each
    __shared__ __align__(16) short sB0[BNB * BK], sB1[BNB * BK];  // 16 KB each
    __shared__ int sTok[BMB];
    __shared__ int sFlag;

    int tid = threadIdx.x;
    int lane = tid & 63;
    if (tid < 64) {
        int f = detect_wave((const unsigned*)inp_, lane);
        if (tid == 0) sFlag = f;
    }
    __syncthreads();
    int flag = sFlag;

    int ntiles = ws[WS_NTILES];
    if (ntiles > MAX_TILES_B) ntiles = MAX_TILES_B;
    if (ntiles < 0) ntiles = 0;
    int items = ntiles * NCOLB;
    const unsigned short* order = (const unsigned short*)(ws + WS_ORDER);
    const char* Abase = flag ? (const char*)ws + WS_BF16_OFF : (const char*)inp_;
    const char* Wbase = flag ? (const char*)ws + WS_BF16_OFF + 2ull * INP_ELEMS
                             : (const char*)weight_;

    int w = tid >> 6;                 // 0..7
    int wm = (w >> 2) * 128;          // 0 or 128 (8 M-frags of 16)
    int wn = (w & 3) * 64;            // 0,64,128,192 (4 N-frags of 16)
    int l15 = lane & 15;
    int quad = lane >> 4;

    // frag read addresses: linear row-major + XOR'd 16B chunk (row-dependent)
    int rowA = wm + l15;
    int rowB = wn + l15;
    int swA = rowA * BK + (quad ^ ((rowA >> 1) & 3)) * 8;
    int swB = rowB * BK + (quad ^ ((rowB >> 1) & 3)) * 8;
    const short* sAr0 = &sA0[swA];
    const short* sAr1 = &sA1[swA];
    const short* sBr0 = &sB0[swB];
    const short* sBr1 = &sB1[swB];

    // staging roles: wave w stages A rows [32w,32w+32) and B rows [32w,32w+32)
    // as 1KB segments {2w,2w+1}. (r+16)>>1 == r>>1 mod 4 -> one XOR term each.
    int sr = lane >> 2;
    int cl = lane & 3;
    int rS0 = w * 32 + sr;
    int rS1 = rS0 + 16;
    int cg = (cl ^ ((rS0 >> 1) & 3)) * 16;    // byte offset of swizzled chunk
    short* dA0_a = &sA0[(2 * w) * 512];
    short* dA1_a = &sA0[(2 * w + 1) * 512];
    short* dB0_a = &sB0[(2 * w) * 512];
    short* dB1_a = &sB0[(2 * w + 1) * 512];
    short* dA0_b = &sA1[(2 * w) * 512];
    short* dA1_b = &sA1[(2 * w + 1) * 512];
    short* dB0_b = &sB1[(2 * w) * 512];
    short* dB1_b = &sB1[(2 * w + 1) * 512];

    // XCD-chunked item partition (gridDim.x = 2048 -> 256 blocks per XCD)
    int xcd = blockIdx.x & 7;
    int sub = blockIdx.x >> 3;
    int chunk = (items + 7) >> 3;

    for (int i = sub; i < chunk; i += 256) {
        int item = xcd * chunk + i;
        if (item >= items) break;
        int tIdx = item >> 1;
        int n0 = (item & 1) * BNB;
        const int* tile = ws + WS_TILES + tIdx * 3;
        int e = tile[0] & 63;
        int start = tile[1];
        int cnt = tile[2];
        cnt = cnt < 1 ? 1 : (cnt > BMB ? BMB : cnt);
        if (start < 0) start = 0;
        if (start > N_TOKENS - cnt) start = N_TOKENS - cnt;

        __syncthreads();   // prev item fully done (protects sTok/LDS)
        if (tid < BMB) {
            int r = tid < cnt ? tid : (cnt - 1);
            sTok[tid] = (int)order[start + r];
        }
        __syncthreads();

        const char* gA0 = Abase + (size_t)sTok[rS0] * (IN_FEAT * 2) + cg;
        const char* gA1 = Abase + (size_t)sTok[rS1] * (IN_FEAT * 2) + cg;
        size_t wbase = (size_t)e * OUT_FEAT * IN_FEAT * 2;
        const char* gB0 = Wbase + wbase + (size_t)(n0 + rS0) * (IN_FEAT * 2) + cg;
        const char* gB1 = Wbase + wbase + (size_t)(n0 + rS1) * (IN_FEAT * 2) + cg;

        f32x4 acc[8][4];
        #pragma unroll
        for (int ii = 0; ii < 8; ++ii)
            #pragma unroll
            for (int jj = 0; jj < 4; ++jj)
                acc[ii][jj] = (f32x4){0.f, 0.f, 0.f, 0.f};

        // prologue: stage step 0 -> buf a, drain, barrier
        STAGE_B(0, dA0_a, dA1_a, dB0_a, dB1_a);
        DRAIN_BARRIER();

        #pragma unroll
        for (int k = 0; k < K_STEPS; ++k) {
            if (k + 1 < K_STEPS) {
                if ((k + 1) & 1) { STAGE_B(k + 1, dA0_b, dA1_b, dB0_b, dB1_b); }
                else             { STAGE_B(k + 1, dA0_a, dA1_a, dB0_a, dB1_a); }
            }
            if (k & 1) { COMPUTE_B(sAr1, sBr1); }
            else       { COMPUTE_B(sAr0, sBr0); }
            if (k + 1 < K_STEPS) {
                DRAIN_BARRIER();   // my stage(k+1) landed + all waves done with buf k
            }
        }

        // epilogue: D col = lane&15, row = quad*4 + reg [m89/m91]; NT stores
        #pragma unroll
        for (int ii = 0; ii < 8; ++ii) {
            int mb = wm + ii * 16 + quad * 4;
            #pragma unroll
            for (int r = 0; r < 4; ++r) {
                int m = mb + r;
                if (m < cnt) {
                    int tok = sTok[m];
                    if (flag) {
                        float* orow = (float*)out_ + (size_t)tok * OUT_FEAT + n0 + wn + l15;
                        #pragma unroll
                        for (int j = 0; j < 4; ++j)
                            __builtin_nontemporal_store(acc[ii][j][r], orow + j * 16);
                    } else {
                        unsigned short* orow = (unsigned short*)out_ + (size_t)tok * OUT_FEAT + n0 + wn + l15;
                        #pragma unroll
                        for (int j = 0; j < 4; ++j)
                            __builtin_nontemporal_store(f2bu(acc[ii][j][r]), orow + j * 16);
                    }
                }
            }
        }
    }
}

// ---------- MID path (meta-only ws): gathers from original inp/weight ----------
__global__ __launch_bounds__(256) void k_moe_gemm_mid(
        const void* __restrict__ inp_,
        const void* __restrict__ weight_,
        void* __restrict__ out_,
        const int* __restrict__ ws) {
    __shared__ __align__(16) short sA[BMM * SK];
    __shared__ __align__(16) short sB[BNM * SK];
    __shared__ int sTok[BMM];
    __shared__ int sFlag;

    int tid = threadIdx.x;
    int lane = tid & 63;
    if (tid < 64) {
        int f = detect_wave((const unsigned*)inp_, lane);
        if (tid == 0) sFlag = f;
    }
    __syncthreads();
    int fp32 = sFlag;

    int ntiles = ws[WS_NTILES];
    if (ntiles > MAX_TILES_M) ntiles = MAX_TILES_M;
    int bx = blockIdx.y;
    if (bx >= ntiles) return;
    const int* tile = ws + WS_TILES + bx * 3;
    int e = tile[0] & 63;
    int start = tile[1];
    int cnt = tile[2];
    cnt = cnt < 1 ? 1 : (cnt > BMM ? BMM : cnt);
    if (start < 0) start = 0;
    if (start > N_TOKENS - cnt) start = N_TOKENS - cnt;
    int n0 = blockIdx.x * BNM;
    const unsigned short* order = (const unsigned short*)(ws + WS_ORDER);

    if (tid < BMM) {
        int r = tid < cnt ? tid : (cnt - 1);
        sTok[tid] = (int)order[start + r];
    }
    __syncthreads();

    int w = tid >> 6;
    int wm = (w >> 1) * 64;
    int wn = (w & 1) * 64;
    int l15 = lane & 15;
    int quad = lane >> 4;

    f32x4 acc[4][4];
    #pragma unroll
    for (int i = 0; i < 4; ++i)
        #pragma unroll
        for (int j = 0; j < 4; ++j)
            acc[i][j] = (f32x4){0.f, 0.f, 0.f, 0.f};

    const short* sAr = &sA[(wm + l15) * SK + quad * 8];
    const short* sBr = &sB[(wn + l15) * SK + quad * 8];

    if (fp32) {
        int ra = tid >> 1;
        int h = tid & 1;
        int tokA = sTok[ra];
        const float4* aG = (const float4*)((const float*)inp_ + (size_t)tokA * IN_FEAT) + h * 4;
        const float4* bG = (const float4*)((const float*)weight_ +
                           (size_t)(e * OUT_FEAT + n0 + ra) * IN_FEAT) + h * 4;
        uint4* sAd = (uint4*)&sA[ra * SK + h * 16];
        uint4* sBd = (uint4*)&sB[ra * SK + h * 16];

        for (int ks = 0; ks < K_STEPS; ++ks) {
            float4 a0 = aG[0], a1 = aG[1], a2 = aG[2], a3 = aG[3];
            float4 b0 = bG[0], b1 = bG[1], b2 = bG[2], b3 = bG[3];
            aG += 8; bG += 8;
            __syncthreads();
            sAd[0] = (uint4){pk2(a0.x, a0.y), pk2(a0.z, a0.w), pk2(a1.x, a1.y), pk2(a1.z, a1.w)};
            sAd[1] = (uint4){pk2(a2.x, a2.y), pk2(a2.z, a2.w), pk2(a3.x, a3.y), pk2(a3.z, a3.w)};
            sBd[0] = (uint4){pk2(b0.x, b0.y), pk2(b0.z, b0.w), pk2(b1.x, b1.y), pk2(b1.z, b1.w)};
            sBd[1] = (uint4){pk2(b2.x, b2.y), pk2(b2.z, b2.w), pk2(b3.x, b3.y), pk2(b3.z, b3.w)};
            __syncthreads();

            bf16x8 a[4], b[4];
            #pragma unroll
            for (int t = 0; t < 4; ++t) {
                a[t] = *(const bf16x8*)(sAr + t * 16 * SK);
                b[t] = *(const bf16x8*)(sBr + t * 16 * SK);
            }
            #pragma unroll
            for (int i = 0; i < 4; ++i)
                #pragma unroll
                for (int j = 0; j < 4; ++j)
                    acc[i][j] = __builtin_amdgcn_mfma_f32_16x16x32_bf16(a[i], b[j], acc[i][j], 0, 0, 0);
        }
    } else {
        int rr = tid >> 2;
        int qc = tid & 3;
        int tokA0 = sTok[rr];
        int tokA1 = sTok[rr + 64];
        const uint4* aG0 = (const uint4*)((const short*)inp_ + (size_t)tokA0 * IN_FEAT) + qc;
        const uint4* aG1 = (const uint4*)((const short*)inp_ + (size_t)tokA1 * IN_FEAT) + qc;
        const uint4* bG0 = (const uint4*)((const short*)weight_ +
                           (size_t)(e * OUT_FEAT + n0 + rr) * IN_FEAT) + qc;
        const uint4* bG1 = (const uint4*)((const short*)weight_ +
                           (size_t)(e * OUT_FEAT + n0 + rr + 64) * IN_FEAT) + qc;
        uint4* sAd0 = (uint4*)&sA[rr * SK + qc * 8];
        uint4* sAd1 = (uint4*)&sA[(rr + 64) * SK + qc * 8];
        uint4* sBd0 = (uint4*)&sB[rr * SK + qc * 8];
        uint4* sBd1 = (uint4*)&sB[(rr + 64) * SK + qc * 8];

        for (int ks = 0; ks < K_STEPS; ++ks) {
            uint4 va0 = *aG0, va1 = *aG1, vb0 = *bG0, vb1 = *bG1;
            aG0 += 4; aG1 += 4; bG0 += 4; bG1 += 4;
            __syncthreads();
            *sAd0 = va0; *sAd1 = va1; *sBd0 = vb0; *sBd1 = vb1;
            __syncthreads();

            bf16x8 a[4], b[4];
            #pragma unroll
            for (int t = 0; t < 4; ++t) {
                a[t] = *(const bf16x8*)(sAr + t * 16 * SK);
                b[t] = *(const bf16x8*)(sBr + t * 16 * SK);
            }
            #pragma unroll
            for (int i = 0; i < 4; ++i)
                #pragma unroll
                for (int j = 0; j < 4; ++j)
                    acc[i][j] = __builtin_amdgcn_mfma_f32_16x16x32_bf16(a[i], b[j], acc[i][j], 0, 0, 0);
        }
    }

    #pragma unroll
    for (int i = 0; i < 4; ++i) {
        int mb = wm + i * 16 + quad * 4;
        #pragma unroll
        for (int r = 0; r < 4; ++r) {
            int m = mb + r;
            if (m < cnt) {
                int tok = sTok[m];
                if (fp32) {
                    float* orow = (float*)out_ + (size_t)tok * OUT_FEAT + n0 + wn + l15;
                    #pragma unroll
                    for (int j = 0; j < 4; ++j)
                        __builtin_nontemporal_store(acc[i][j][r], orow + j * 16);
                } else {
                    unsigned short* orow = (unsigned short*)out_ + (size_t)tok * OUT_FEAT + n0 + wn + l15;
                    #pragma unroll
                    for (int j = 0; j < 4; ++j)
                        __builtin_nontemporal_store(f2bu(acc[i][j][r]), orow + j * 16);
                }
            }
        }
    }
}

// ws-light fallback: one block per token, VALU dot products
__global__ __launch_bounds__(256) void k_gemv(
        const void* __restrict__ inp_,
        const int* __restrict__ gate,
        const void* __restrict__ weight_,
        void* __restrict__ out_) {
    __shared__ float xf[IN_FEAT];
    __shared__ int sFlag;
    int t = threadIdx.x;
    if (t < 64) {
        int f = detect_wave((const unsigned*)inp_, t);
        if (t == 0) sFlag = f;
    }
    __syncthreads();
    int fp32 = sFlag;
    int tok = blockIdx.x;
    int e = gate[tok] & 63;
    if (fp32) {
        const float* xr = (const float*)inp_ + (size_t)tok * IN_FEAT;
        xf[2 * t] = xr[2 * t];
        xf[2 * t + 1] = xr[2 * t + 1];
        __syncthreads();
        #pragma unroll
        for (int rep = 0; rep < 2; ++rep) {
            int o = t + rep * 256;
            float s = 0.f;
            const float4* wr = (const float4*)((const float*)weight_ +
                               (size_t)(e * OUT_FEAT + o) * IN_FEAT);
            for (int k4 = 0; k4 < IN_FEAT / 4; ++k4) {
                float4 q = wr[k4];
                s += xf[4 * k4] * q.x + xf[4 * k4 + 1] * q.y
                   + xf[4 * k4 + 2] * q.z + xf[4 * k4 + 3] * q.w;
            }
            ((float*)out_)[(size_t)tok * OUT_FEAT + o] = s;
        }
    } else {
        const short* xr = (const short*)inp_ + (size_t)tok * IN_FEAT;
        xf[2 * t] = b2f(xr[2 * t]);
        xf[2 * t + 1] = b2f(xr[2 * t + 1]);
        __syncthreads();
        #pragma unroll
        for (int rep = 0; rep < 2; ++rep) {
            int o = t + rep * 256;
            float s = 0.f;
            const short4* wr = (const short4*)((const short*)weight_ +
                               (size_t)(e * OUT_FEAT + o) * IN_FEAT);
            for (int k4 = 0; k4 < IN_FEAT / 4; ++k4) {
                short4 q = wr[k4];
                s += xf[4 * k4] * b2f(q.x) + xf[4 * k4 + 1] * b2f(q.y)
                   + xf[4 * k4 + 2] * b2f(q.z) + xf[4 * k4 + 3] * b2f(q.w);
            }
            ((__hip_bfloat16*)out_)[(size_t)tok * OUT_FEAT + o] = __float2bfloat16(s);
        }
    }
}

extern "C" void kernel_launch(void* const* d_in, const int* in_sizes, int n_in,
                              void* d_out, int out_size, void* d_ws, size_t ws_size,
                              hipStream_t stream) {
    const void* inp    = d_in[0];
    const int*  gate   = (const int*)d_in[1];
    const void* weight = d_in[2];
    int* ws = (int*)d_ws;

    if (ws_size >= WS_BIG) {
        k_count<<<NRANGE, 256, 0, stream>>>(gate, ws);
        k_plan_cvt<<<2048, 256, 0, stream>>>(gate, inp, weight, ws, 1, 8);  // BM=256 tiles
        k_moe_gemm_big<<<2048, 512, 0, stream>>>(inp, weight, d_out, ws);
    } else if (ws_size >= (size_t)WS_META_NEEDED) {
        k_count<<<NRANGE, 256, 0, stream>>>(gate, ws);
        k_plan_cvt<<<NRANGE, 256, 0, stream>>>(gate, inp, weight, ws, 0, 7); // BM=128 tiles
        dim3 grid(NCOLM, MAX_TILES_M);
        k_moe_gemm_mid<<<grid, 256, 0, stream>>>(inp, weight, d_out, ws);
    } else {
        k_gemv<<<N_TOKENS, 256, 0, stream>>>(inp, gate, weight, d_out);
    }
}

// Round 10
// 327.786 us; speedup vs baseline: 1.0315x; 1.0315x over previous
//
#include <hip/hip_runtime.h>
#include <hip/hip_bf16.h>
#include <stdint.h>

#define N_TOKENS   65536
#define IN_FEAT    512
#define OUT_FEAT   512
#define NUM_EXPERT 64
#define BM 128
#define BN 128
#define BK 32
#define SK 36                    // padded LDS stride (mid-path kernel only)
#define K_STEPS (IN_FEAT / BK)   // 16
#define MAX_TILES 640            // true worst case: 512 + 64 = 576 tiles
#define NCOL (OUT_FEAT / BN)     // 4
#define NRANGE 256               // token ranges (256 tokens each)
#define CVT_BLKS 2048            // dedicated conversion blocks (grid = NRANGE + CVT_BLKS)

// ws layout (int32 units):
//   [197] tile_count  [200..1928) tiles (e,start,cnt)x576
//   [2048..34816)  order ushort[65536] (128 KB)
//   [34816..51200) counts matrix cnt[range][expert] = 256x64 ints (64 KB)
// BIG extension (byte offsets):
//   [212992 ..)              bf16 copy of inp, TOKEN order (67,108,864 B)
//   [212992+2*INP_ELEMS ..)  bf16 copy of weight (33,554,432 B)
#define WS_NTILES 197
#define WS_TILES  200
#define WS_ORDER  2048
#define WS_CNT    34816
#define WS_META_NEEDED 204800    // bytes: through end of counts matrix

#define INP_ELEMS (N_TOKENS * IN_FEAT)               // 33,554,432
#define W_ELEMS   (NUM_EXPERT * OUT_FEAT * IN_FEAT)  // 16,777,216
#define WS_BF16_OFF 212992
#define WS_BIG ((size_t)WS_BF16_OFF + 2ull * INP_ELEMS + 2ull * W_ELEMS)  // ~100.9 MB

typedef __attribute__((ext_vector_type(8))) short bf16x8;
typedef __attribute__((ext_vector_type(4))) float f32x4;

__device__ __forceinline__ float b2f(short v) {
    union { float f; unsigned u; } z;
    z.u = ((unsigned)(unsigned short)v) << 16;
    return z.f;
}

__device__ __forceinline__ unsigned pk2(float a, float b) {
    union { __hip_bfloat16 h; unsigned short u; } x, y;
    x.h = __float2bfloat16(a);
    y.h = __float2bfloat16(b);
    return ((unsigned)y.u << 16) | (unsigned)x.u;
}

__device__ __forceinline__ unsigned short f2bu(float a) {
    union { __hip_bfloat16 h; unsigned short u; } x;
    x.h = __float2bfloat16(a);
    return x.u;
}

// async global->LDS, 16B per lane; LDS dest is wave-uniform base + lane*16
__device__ __forceinline__ void gll16(const void* g, short* l) {
    __builtin_amdgcn_global_load_lds(
        (const __attribute__((address_space(1))) unsigned*)g,
        (__attribute__((address_space(3))) unsigned*)l, 16, 0, 0);
}

// dtype detect by one wave: bf16-pair data has low-u16 exponent fields in the
// plausible band; fp32 low-u16 is random mantissa bits. Deterministic.
__device__ __forceinline__ int detect_wave(const unsigned* __restrict__ inw, int lane) {
    int cnt = 0;
    #pragma unroll
    for (int i = 0; i < 16; ++i) {
        unsigned u = inw[lane * 16 + i];
        unsigned lo = u & 0xFFFFu;
        unsigned ec = (lo >> 7) & 0xFFu;
        if (lo == 0u || (ec >= 90u && ec <= 131u)) cnt++;
    }
    #pragma unroll
    for (int d = 32; d > 0; d >>= 1) cnt += __shfl_down(cnt, d, 64);
    return (cnt >= 512) ? 0 : 1;   // valid on lane 0: 0=bf16, 1=fp32
}

// ---------------------------------------------------------------------------
// k_count: 256 blocks, each histograms its own 256-token range. ~3 us.
// ---------------------------------------------------------------------------
__global__ __launch_bounds__(256) void k_count(const int* __restrict__ gate,
                                               int* __restrict__ ws) {
    __shared__ int h[NUM_EXPERT];
    int t = threadIdx.x;
    if (t < NUM_EXPERT) h[t] = 0;
    __syncthreads();
    int g = gate[blockIdx.x * 256 + t] & 63;
    atomicAdd(&h[g], 1);
    __syncthreads();
    if (t < NUM_EXPERT) ws[WS_CNT + blockIdx.x * 64 + t] = h[t];
}

// ---------------------------------------------------------------------------
// k_prep (grid = NRANGE + CVT_BLKS):
//   blocks 0..255     : plan from counts matrix (L2-hot), rank own 256 tokens
//                       via LDS cursors, write order; block 0 writes tile
//                       descriptors. ~10 us, fully hidden under conversion.
//   blocks 256..2303  : (big+fp32) streaming fp32->bf16 conversion of inp
//                       (TOKEN order) then weight; NT loads on the read-once
//                       fp32 sources, normal stores keep bf16 copies LLC-hot.
//                       Dedicated blocks (plan blocks do NOT join): conversion
//                       starts at full width immediately, no plan straggler.
//                       Unroll x2 with both loads issued before stores (ILP).
// ---------------------------------------------------------------------------
__global__ __launch_bounds__(256) void k_prep(
        const int* __restrict__ gate,
        const void* __restrict__ inp_,
        const void* __restrict__ weight_,
        int* __restrict__ ws,
        int big) {
    __shared__ int sFlag;
    int t = threadIdx.x;
    int lane = t & 63;
    if (t < 64) {
        int f = detect_wave((const unsigned*)inp_, lane);
        if (t == 0) sFlag = f;
    }
    __syncthreads();
    int flag = sFlag;

    if (blockIdx.x < NRANGE) {
        // ---- plan (redundant per block, all derive identical values) ----
        __shared__ int pAll[4][NUM_EXPERT];
        __shared__ int pPre[4][NUM_EXPERT];
        __shared__ int sCur[NUM_EXPERT];
        int b = blockIdx.x;
        int e = t & 63;
        int q = t >> 6;
        const int* cnt = ws + WS_CNT;
        int sAll = 0, sPre = 0;
        for (int r = q * 64; r < q * 64 + 64; ++r) {
            int v = cnt[r * 64 + e];
            sAll += v;
            if (r < b) sPre += v;
        }
        pAll[q][e] = sAll;
        pPre[q][e] = sPre;
        __syncthreads();
        if (t < 64) {
            int T = pAll[0][lane] + pAll[1][lane] + pAll[2][lane] + pAll[3][lane];
            int P = pPre[0][lane] + pPre[1][lane] + pPre[2][lane] + pPre[3][lane];
            int ps = T;
            #pragma unroll
            for (int d = 1; d < 64; d <<= 1) { int v = __shfl_up(ps, d, 64); if (lane >= d) ps += v; }
            int off = ps - T;            // exclusive token prefix of expert `lane`
            sCur[lane] = off + P;        // this block's base for expert `lane`
            if (b == 0) {
                int nt = (T + BM - 1) >> 7;
                int pt = nt;
                #pragma unroll
                for (int d = 1; d < 64; d <<= 1) { int v = __shfl_up(pt, d, 64); if (lane >= d) pt += v; }
                int tb = pt - nt;
                for (int j = 0; j < nt; ++j) {
                    int* tp = ws + WS_TILES + (tb + j) * 3;
                    tp[0] = lane;
                    tp[1] = off + j * BM;
                    int rem = T - j * BM;
                    tp[2] = rem < BM ? rem : BM;
                }
                if (lane == 63) ws[WS_NTILES] = pt;
            }
        }
        __syncthreads();

        // ---- rank own 256 tokens (LDS cursors; intra-block order arbitrary;
        //      out[tok] is position-independent -> deterministic output) ----
        unsigned short* order = (unsigned short*)(ws + WS_ORDER);
        int tok = b * 256 + t;
        int ge = gate[tok] & 63;
        int pos = atomicAdd(&sCur[ge], 1);
        if ((unsigned)pos < (unsigned)N_TOKENS) order[pos] = (unsigned short)tok;
        return;   // plan blocks do NOT join conversion
    }

    // ---- streaming conversion (big + fp32 only), blocks 256..2303 ----
    if (!big || flag != 1) return;
    const float* inpf = (const float*)inp_;
    const float* wf   = (const float*)weight_;
    short* bi = (short*)((char*)ws + WS_BF16_OFF);
    short* bw = bi + INP_ELEMS;
    long long base = ((long long)blockIdx.x - NRANGE) * 256 + t;
    const long long stride = (long long)CVT_BLKS * 256;   // 524288

    // inp: INP_ELEMS/8 = 4,194,304 chunks -> exactly 8 per thread (4 pairs)
    const long long NCI = (long long)INP_ELEMS / 8;
    for (long long c = base; c < NCI; c += 2 * stride) {
        long long c2 = c + stride;
        const f32x4* s0 = (const f32x4*)(inpf + c * 8);
        f32x4 x0 = __builtin_nontemporal_load(s0);
        f32x4 y0 = __builtin_nontemporal_load(s0 + 1);
        f32x4 x1, y1;
        if (c2 < NCI) {
            const f32x4* s1 = (const f32x4*)(inpf + c2 * 8);
            x1 = __builtin_nontemporal_load(s1);
            y1 = __builtin_nontemporal_load(s1 + 1);
        }
        *(uint4*)(bi + c * 8) = (uint4){pk2(x0[0], x0[1]), pk2(x0[2], x0[3]),
                                        pk2(y0[0], y0[1]), pk2(y0[2], y0[3])};
        if (c2 < NCI)
            *(uint4*)(bi + c2 * 8) = (uint4){pk2(x1[0], x1[1]), pk2(x1[2], x1[3]),
                                             pk2(y1[0], y1[1]), pk2(y1[2], y1[3])};
    }
    // weight: W_ELEMS/8 = 2,097,152 chunks -> exactly 4 per thread (2 pairs)
    const long long NCW = (long long)W_ELEMS / 8;
    for (long long c = base; c < NCW; c += 2 * stride) {
        long long c2 = c + stride;
        const f32x4* s0 = (const f32x4*)(wf + c * 8);
        f32x4 x0 = __builtin_nontemporal_load(s0);
        f32x4 y0 = __builtin_nontemporal_load(s0 + 1);
        f32x4 x1, y1;
        if (c2 < NCW) {
            const f32x4* s1 = (const f32x4*)(wf + c2 * 8);
            x1 = __builtin_nontemporal_load(s1);
            y1 = __builtin_nontemporal_load(s1 + 1);
        }
        *(uint4*)(bw + c * 8) = (uint4){pk2(x0[0], x0[1]), pk2(x0[2], x0[3]),
                                        pk2(y0[0], y0[1]), pk2(y0[2], y0[3])};
        if (c2 < NCW)
            *(uint4*)(bw + c2 * 8) = (uint4){pk2(x1[0], x1[1]), pk2(x1[2], x1[3]),
                                             pk2(y1[0], y1[1]), pk2(y1[2], y1[3])};
    }
}

#define COMPUTE(pA, pB)                                                        \
    {                                                                          \
        bf16x8 a_[4], b_[4];                                                   \
        _Pragma("unroll")                                                      \
        for (int t2 = 0; t2 < 4; ++t2) {                                       \
            a_[t2] = *(const bf16x8*)((pA) + t2 * 16 * BK);                    \
            b_[t2] = *(const bf16x8*)((pB) + t2 * 16 * BK);                    \
        }                                                                      \
        _Pragma("unroll")                                                      \
        for (int i_ = 0; i_ < 4; ++i_)                                         \
            _Pragma("unroll")                                                  \
            for (int j_ = 0; j_ < 4; ++j_)                                     \
                acc[i_][j_] = __builtin_amdgcn_mfma_f32_16x16x32_bf16(         \
                    a_[i_], b_[j_], acc[i_][j_], 0, 0, 0);                     \
    }

#define STAGE(kk, pa, pb)                                                      \
    gll16(gA0 + (size_t)(kk) * 64, (pa));                                      \
    gll16(gA1 + (size_t)(kk) * 64, (pa) + 512);                                \
    gll16(gB0 + (size_t)(kk) * 64, (pb));                                      \
    gll16(gB1 + (size_t)(kk) * 64, (pb) + 512);

// Fenced drain + barrier: vmcnt(0) (all this wave's LDS-DMA landed) then
// s_barrier (all waves reached the same point). Both carry "memory" clobbers
// so the compiler cannot move LDS reads/writes or gll16 across them (rule #18
// class). R4/R7-proven structure; counted-vmcnt(4) raced on HW (R5/R6).
#define DRAIN_BARRIER()                                                        \
    asm volatile("s_waitcnt vmcnt(0)" ::: "memory");                           \
    asm volatile("s_barrier" ::: "memory")

// ---------- BIG path GEMM: 128x128 tile, 256 threads (measured optimum) ----------
// R7/R8/R9 comparison: this config (33 KB LDS, VGPR 64, 4 blk/CU) beats both
// BN=256 (50 KB, 3 blk/CU) and BM=256 (67 KB, 2 blk/CU) — the drain-to-0
// pipeline is latency-bound, so occupancy > staged-byte reduction.
// Per K-step: issue STAGE(k+1) into the other buffer, COMPUTE(k) (the stage
// loads drain UNDER the MFMAs), then vmcnt(0)+barrier. One barrier per step.
// Source-side XOR chunk swizzle + same XOR on frag reads -> ~2 lanes/bank.
// Items XCD-chunked: the 4 column-items of a tile share the same XCD's L2.
__global__ __launch_bounds__(256) void k_moe_gemm_big(
        const void* __restrict__ inp_,
        const void* __restrict__ weight_,
        void* __restrict__ out_,
        const int* __restrict__ ws) {
    __shared__ __align__(16) short sA0[BM * BK], sA1[BM * BK];  // 8 KB each
    __shared__ __align__(16) short sB0[BN * BK], sB1[BN * BK];
    __shared__ int sTok[BM];
    __shared__ int sFlag;

    int tid = threadIdx.x;
    int lane = tid & 63;
    if (tid < 64) {
        int f = detect_wave((const unsigned*)inp_, lane);
        if (tid == 0) sFlag = f;
    }
    __syncthreads();
    int flag = sFlag;

    int ntiles = ws[WS_NTILES];
    if (ntiles > MAX_TILES) ntiles = MAX_TILES;
    if (ntiles < 0) ntiles = 0;
    int items = ntiles * NCOL;
    const unsigned short* order = (const unsigned short*)(ws + WS_ORDER);
    const char* Abase = flag ? (const char*)ws + WS_BF16_OFF : (const char*)inp_;
    const char* Wbase = flag ? (const char*)ws + WS_BF16_OFF + 2ull * INP_ELEMS
                             : (const char*)weight_;

    int w = tid >> 6;
    int wm = (w >> 1) * 64;
    int wn = (w & 1) * 64;
    int l15 = lane & 15;
    int quad = lane >> 4;

    // frag read addresses: linear row-major + XOR'd 16B chunk (row-dependent)
    int rowA = wm + l15;
    int rowB = wn + l15;
    int swA = rowA * BK + (quad ^ ((rowA >> 1) & 3)) * 8;
    int swB = rowB * BK + (quad ^ ((rowB >> 1) & 3)) * 8;
    const short* sAr0 = &sA0[swA];
    const short* sAr1 = &sA1[swA];
    const short* sBr0 = &sB0[swB];
    const short* sBr1 = &sB1[swB];

    // staging roles: wave w stages 1KB segments {2w,2w+1} of A and B
    int sr = lane >> 2;
    int cl = lane & 3;
    int rS0 = w * 32 + sr;
    int rS1 = rS0 + 16;
    int cg0 = (cl ^ ((rS0 >> 1) & 3)) * 16;   // byte offset of swizzled chunk
    int cg1 = (cl ^ ((rS1 >> 1) & 3)) * 16;
    short* dA0 = &sA0[w * 1024];
    short* dB0 = &sB0[w * 1024];
    short* dA1 = &sA1[w * 1024];
    short* dB1 = &sB1[w * 1024];

    // XCD-chunked item partition (gridDim.x = 2048 -> 256 blocks per XCD)
    int xcd = blockIdx.x & 7;
    int sub = blockIdx.x >> 3;
    int chunk = (items + 7) >> 3;

    for (int i = sub; i < chunk; i += 256) {
        int item = xcd * chunk + i;
        if (item >= items) break;
        int tIdx = item >> 2;
        int n0 = (item & 3) * BN;
        const int* tile = ws + WS_TILES + tIdx * 3;
        int e = tile[0] & 63;
        int start = tile[1];
        int cnt = tile[2];
        cnt = cnt < 1 ? 1 : (cnt > BM ? BM : cnt);
        if (start < 0) start = 0;
        if (start > N_TOKENS - cnt) start = N_TOKENS - cnt;

        __syncthreads();   // prev item fully done (full drain; protects sTok/LDS)
        if (tid < BM) {
            int r = tid < cnt ? tid : (cnt - 1);
            sTok[tid] = (int)order[start + r];
        }
        __syncthreads();

        const char* gA0 = Abase + (size_t)sTok[rS0] * (IN_FEAT * 2) + cg0;
        const char* gA1 = Abase + (size_t)sTok[rS1] * (IN_FEAT * 2) + cg1;
        size_t wbase = (size_t)e * OUT_FEAT * IN_FEAT * 2;
        const char* gB0 = Wbase + wbase + (size_t)(n0 + rS0) * (IN_FEAT * 2) + cg0;
        const char* gB1 = Wbase + wbase + (size_t)(n0 + rS1) * (IN_FEAT * 2) + cg1;

        f32x4 acc[4][4];
        #pragma unroll
        for (int ii = 0; ii < 4; ++ii)
            #pragma unroll
            for (int jj = 0; jj < 4; ++jj)
                acc[ii][jj] = (f32x4){0.f, 0.f, 0.f, 0.f};

        // prologue: stage step 0 -> buf 0, drain, barrier
        STAGE(0, dA0, dB0);
        DRAIN_BARRIER();

        #pragma unroll
        for (int k = 0; k < K_STEPS; ++k) {
            // issue next stage into the OTHER buffer (its last readers finished
            // at the barrier ending step k-1)
            if (k + 1 < K_STEPS) {
                if ((k + 1) & 1) { STAGE(k + 1, dA1, dB1); }
                else             { STAGE(k + 1, dA0, dB0); }
            }
            // compute current buffer; next-stage loads drain under the MFMAs
            if (k & 1) { COMPUTE(sAr1, sBr1); }
            else       { COMPUTE(sAr0, sBr0); }
            if (k + 1 < K_STEPS) {
                DRAIN_BARRIER();   // my stage(k+1) landed + all waves done reading buf k
            }
        }

        // epilogue: D col = lane&15, row = quad*4 + reg [m89/m91]; NT stores
        #pragma unroll
        for (int ii = 0; ii < 4; ++ii) {
            int mb = wm + ii * 16 + quad * 4;
            #pragma unroll
            for (int r = 0; r < 4; ++r) {
                int m = mb + r;
                if (m < cnt) {
                    int tok = sTok[m];
                    if (flag) {
                        float* orow = (float*)out_ + (size_t)tok * OUT_FEAT + n0 + wn + l15;
                        #pragma unroll
                        for (int j = 0; j < 4; ++j)
                            __builtin_nontemporal_store(acc[ii][j][r], orow + j * 16);
                    } else {
                        unsigned short* orow = (unsigned short*)out_ + (size_t)tok * OUT_FEAT + n0 + wn + l15;
                        #pragma unroll
                        for (int j = 0; j < 4; ++j)
                            __builtin_nontemporal_store(f2bu(acc[ii][j][r]), orow + j * 16);
                    }
                }
            }
        }
    }
}

// ---------- MID path (meta-only ws): gathers from original inp/weight ----------
__global__ __launch_bounds__(256) void k_moe_gemm_mid(
        const void* __restrict__ inp_,
        const void* __restrict__ weight_,
        void* __restrict__ out_,
        const int* __restrict__ ws) {
    __shared__ __align__(16) short sA[BM * SK];
    __shared__ __align__(16) short sB[BN * SK];
    __shared__ int sTok[BM];
    __shared__ int sFlag;

    int tid = threadIdx.x;
    int lane = tid & 63;
    if (tid < 64) {
        int f = detect_wave((const unsigned*)inp_, lane);
        if (tid == 0) sFlag = f;
    }
    __syncthreads();
    int fp32 = sFlag;

    int ntiles = ws[WS_NTILES];
    if (ntiles > MAX_TILES) ntiles = MAX_TILES;
    int bx = blockIdx.y;
    if (bx >= ntiles) return;
    const int* tile = ws + WS_TILES + bx * 3;
    int e = tile[0] & 63;
    int start = tile[1];
    int cnt = tile[2];
    cnt = cnt < 1 ? 1 : (cnt > BM ? BM : cnt);
    if (start < 0) start = 0;
    if (start > N_TOKENS - cnt) start = N_TOKENS - cnt;
    int n0 = blockIdx.x * BN;
    const unsigned short* order = (const unsigned short*)(ws + WS_ORDER);

    if (tid < BM) {
        int r = tid < cnt ? tid : (cnt - 1);
        sTok[tid] = (int)order[start + r];
    }
    __syncthreads();

    int w = tid >> 6;
    int wm = (w >> 1) * 64;
    int wn = (w & 1) * 64;
    int l15 = lane & 15;
    int quad = lane >> 4;

    f32x4 acc[4][4];
    #pragma unroll
    for (int i = 0; i < 4; ++i)
        #pragma unroll
        for (int j = 0; j < 4; ++j)
            acc[i][j] = (f32x4){0.f, 0.f, 0.f, 0.f};

    const short* sAr = &sA[(wm + l15) * SK + quad * 8];
    const short* sBr = &sB[(wn + l15) * SK + quad * 8];

    if (fp32) {
        int ra = tid >> 1;
        int h = tid & 1;
        int tokA = sTok[ra];
        const float4* aG = (const float4*)((const float*)inp_ + (size_t)tokA * IN_FEAT) + h * 4;
        const float4* bG = (const float4*)((const float*)weight_ +
                           (size_t)(e * OUT_FEAT + n0 + ra) * IN_FEAT) + h * 4;
        uint4* sAd = (uint4*)&sA[ra * SK + h * 16];
        uint4* sBd = (uint4*)&sB[ra * SK + h * 16];

        for (int ks = 0; ks < K_STEPS; ++ks) {
            float4 a0 = aG[0], a1 = aG[1], a2 = aG[2], a3 = aG[3];
            float4 b0 = bG[0], b1 = bG[1], b2 = bG[2], b3 = bG[3];
            aG += 8; bG += 8;
            __syncthreads();
            sAd[0] = (uint4){pk2(a0.x, a0.y), pk2(a0.z, a0.w), pk2(a1.x, a1.y), pk2(a1.z, a1.w)};
            sAd[1] = (uint4){pk2(a2.x, a2.y), pk2(a2.z, a2.w), pk2(a3.x, a3.y), pk2(a3.z, a3.w)};
            sBd[0] = (uint4){pk2(b0.x, b0.y), pk2(b0.z, b0.w), pk2(b1.x, b1.y), pk2(b1.z, b1.w)};
            sBd[1] = (uint4){pk2(b2.x, b2.y), pk2(b2.z, b2.w), pk2(b3.x, b3.y), pk2(b3.z, b3.w)};
            __syncthreads();

            bf16x8 a[4], b[4];
            #pragma unroll
            for (int t = 0; t < 4; ++t) {
                a[t] = *(const bf16x8*)(sAr + t * 16 * SK);
                b[t] = *(const bf16x8*)(sBr + t * 16 * SK);
            }
            #pragma unroll
            for (int i = 0; i < 4; ++i)
                #pragma unroll
                for (int j = 0; j < 4; ++j)
                    acc[i][j] = __builtin_amdgcn_mfma_f32_16x16x32_bf16(a[i], b[j], acc[i][j], 0, 0, 0);
        }
    } else {
        int rr = tid >> 2;
        int qc = tid & 3;
        int tokA0 = sTok[rr];
        int tokA1 = sTok[rr + 64];
        const uint4* aG0 = (const uint4*)((const short*)inp_ + (size_t)tokA0 * IN_FEAT) + qc;
        const uint4* aG1 = (const uint4*)((const short*)inp_ + (size_t)tokA1 * IN_FEAT) + qc;
        const uint4* bG0 = (const uint4*)((const short*)weight_ +
                           (size_t)(e * OUT_FEAT + n0 + rr) * IN_FEAT) + qc;
        const uint4* bG1 = (const uint4*)((const short*)weight_ +
                           (size_t)(e * OUT_FEAT + n0 + rr + 64) * IN_FEAT) + qc;
        uint4* sAd0 = (uint4*)&sA[rr * SK + qc * 8];
        uint4* sAd1 = (uint4*)&sA[(rr + 64) * SK + qc * 8];
        uint4* sBd0 = (uint4*)&sB[rr * SK + qc * 8];
        uint4* sBd1 = (uint4*)&sB[(rr + 64) * SK + qc * 8];

        for (int ks = 0; ks < K_STEPS; ++ks) {
            uint4 va0 = *aG0, va1 = *aG1, vb0 = *bG0, vb1 = *bG1;
            aG0 += 4; aG1 += 4; bG0 += 4; bG1 += 4;
            __syncthreads();
            *sAd0 = va0; *sAd1 = va1; *sBd0 = vb0; *sBd1 = vb1;
            __syncthreads();

            bf16x8 a[4], b[4];
            #pragma unroll
            for (int t = 0; t < 4; ++t) {
                a[t] = *(const bf16x8*)(sAr + t * 16 * SK);
                b[t] = *(const bf16x8*)(sBr + t * 16 * SK);
            }
            #pragma unroll
            for (int i = 0; i < 4; ++i)
                #pragma unroll
                for (int j = 0; j < 4; ++j)
                    acc[i][j] = __builtin_amdgcn_mfma_f32_16x16x32_bf16(a[i], b[j], acc[i][j], 0, 0, 0);
        }
    }

    #pragma unroll
    for (int i = 0; i < 4; ++i) {
        int mb = wm + i * 16 + quad * 4;
        #pragma unroll
        for (int r = 0; r < 4; ++r) {
            int m = mb + r;
            if (m < cnt) {
                int tok = sTok[m];
                if (fp32) {
                    float* orow = (float*)out_ + (size_t)tok * OUT_FEAT + n0 + wn + l15;
                    #pragma unroll
                    for (int j = 0; j < 4; ++j)
                        __builtin_nontemporal_store(acc[i][j][r], orow + j * 16);
                } else {
                    unsigned short* orow = (unsigned short*)out_ + (size_t)tok * OUT_FEAT + n0 + wn + l15;
                    #pragma unroll
                    for (int j = 0; j < 4; ++j)
                        __builtin_nontemporal_store(f2bu(acc[i][j][r]), orow + j * 16);
                }
            }
        }
    }
}

// ws-light fallback: one block per token, VALU dot products
__global__ __launch_bounds__(256) void k_gemv(
        const void* __restrict__ inp_,
        const int* __restrict__ gate,
        const void* __restrict__ weight_,
        void* __restrict__ out_) {
    __shared__ float xf[IN_FEAT];
    __shared__ int sFlag;
    int t = threadIdx.x;
    if (t < 64) {
        int f = detect_wave((const unsigned*)inp_, t);
        if (t == 0) sFlag = f;
    }
    __syncthreads();
    int fp32 = sFlag;
    int tok = blockIdx.x;
    int e = gate[tok] & 63;
    if (fp32) {
        const float* xr = (const float*)inp_ + (size_t)tok * IN_FEAT;
        xf[2 * t] = xr[2 * t];
        xf[2 * t + 1] = xr[2 * t + 1];
        __syncthreads();
        #pragma unroll
        for (int rep = 0; rep < 2; ++rep) {
            int o = t + rep * 256;
            float s = 0.f;
            const float4* wr = (const float4*)((const float*)weight_ +
                               (size_t)(e * OUT_FEAT + o) * IN_FEAT);
            for (int k4 = 0; k4 < IN_FEAT / 4; ++k4) {
                float4 q = wr[k4];
                s += xf[4 * k4] * q.x + xf[4 * k4 + 1] * q.y
                   + xf[4 * k4 + 2] * q.z + xf[4 * k4 + 3] * q.w;
            }
            ((float*)out_)[(size_t)tok * OUT_FEAT + o] = s;
        }
    } else {
        const short* xr = (const short*)inp_ + (size_t)tok * IN_FEAT;
        xf[2 * t] = b2f(xr[2 * t]);
        xf[2 * t + 1] = b2f(xr[2 * t + 1]);
        __syncthreads();
        #pragma unroll
        for (int rep = 0; rep < 2; ++rep) {
            int o = t + rep * 256;
            float s = 0.f;
            const short4* wr = (const short4*)((const short*)weight_ +
                               (size_t)(e * OUT_FEAT + o) * IN_FEAT);
            for (int k4 = 0; k4 < IN_FEAT / 4; ++k4) {
                short4 q = wr[k4];
                s += xf[4 * k4] * b2f(q.x) + xf[4 * k4 + 1] * b2f(q.y)
                   + xf[4 * k4 + 2] * b2f(q.z) + xf[4 * k4 + 3] * b2f(q.w);
            }
            ((__hip_bfloat16*)out_)[(size_t)tok * OUT_FEAT + o] = __float2bfloat16(s);
        }
    }
}

extern "C" void kernel_launch(void* const* d_in, const int* in_sizes, int n_in,
                              void* d_out, int out_size, void* d_ws, size_t ws_size,
                              hipStream_t stream) {
    const void* inp    = d_in[0];
    const int*  gate   = (const int*)d_in[1];
    const void* weight = d_in[2];
    int* ws = (int*)d_ws;

    if (ws_size >= WS_BIG) {
        k_count<<<NRANGE, 256, 0, stream>>>(gate, ws);
        k_prep<<<NRANGE + CVT_BLKS, 256, 0, stream>>>(gate, inp, weight, ws, 1);
        k_moe_gemm_big<<<2048, 256, 0, stream>>>(inp, weight, d_out, ws);
    } else if (ws_size >= (size_t)WS_META_NEEDED) {
        k_count<<<NRANGE, 256, 0, stream>>>(gate, ws);
        k_prep<<<NRANGE, 256, 0, stream>>>(gate, inp, weight, ws, 0);
        dim3 grid(NCOL, MAX_TILES);
        k_moe_gemm_mid<<<grid, 256, 0, stream>>>(inp, weight, d_out, ws);
    } else {
        k_gemv<<<N_TOKENS, 256, 0, stream>>>(inp, gate, weight, d_out);
    }
}